// Round 5
// baseline (134.575 us; speedup 1.0000x reference)
//
#include <hip/hip_runtime.h>

// input_tensor: [8,128,128,128,1] fp32 ; random_u: [8,8,3] fp32 ; SCALE=0.2
#define NB   8
#define NS   128
#define VOX  (NS*NS*NS)

// Tile 32w x 8h x 8d. Affine coeff bounds (A^T A = 8I closed form):
//   t_diag in [0.8,1.0], |t_offdiag| <= 0.1, |t_trans| <= 0.1.
// Pixel-space spans over tile offsets (kd<=7, kh<=7, kw<=31):
//   p0 span <= 7*1 + 7*0.1 + 31*0.1 = 10.8 -> floor-index span <= 11
//   p1 span <= 10.8 -> <= 11
//   p2 span <= 7*0.1 + 7*0.1 + 31*1 = 32.4 -> floor-index span <= 33
// Windows (fixed size -> compile-time LDS strides):
//   d: [d_lo, d_lo+13], d_lo = clamp(i0mn-1, 0, 114): covers [i0mn-1, i0mx+2]
//   h: same, SH = 14
//   w: ws = clamp(max(i2mn-1,0) & ~3, 0, 88): needed i2mx+1-ws <= 33+1+4 = 38 < 40
#define SD    14
#define SH    14
#define ROW_W 40
#define RST   (SH*ROW_W)     // 560, compile-time constant

typedef __attribute__((address_space(1))) const void gconst_t;
typedef __attribute__((address_space(3))) void lds_t;

__global__ __launch_bounds__(256) void warp_resample_kernel(
        const float* __restrict__ img, const float* __restrict__ u,
        float* __restrict__ out) {
    __shared__ float tm[12];
    __shared__ __align__(16) float slab[SD * RST];   // 31,360 B

    const int tid  = threadIdx.x;
    const int bi   = blockIdx.x;
    const int wblk =  bi       & 3;    // 4 w-tiles of 32
    const int hblk = (bi >> 2) & 15;   // 16 h-tiles of 8
    const int dblk = (bi >> 6) & 15;   // 16 d-tiles of 8
    const int b    =  bi >> 10;        // 8 batches

    // ---- affine transform from noise (A^T A = 8I -> closed form), 12 lanes ----
    if (tid < 12) {
        int i = tid >> 2, j = tid & 3;
        float acc = 0.f;
#pragma unroll
        for (int n = 0; n < 8; ++n) {
            float ci = (n & (4 >> i)) ? 1.f : -1.f;
            float cj = (j < 3) ? ((n & (4 >> j)) ? 1.f : -1.f) : 1.f;
            float s  = 0.8f + 0.2f * u[(b * 8 + n) * 3 + i];
            acc += cj * ci * s;
        }
        tm[tid] = acc * 0.125f;
    }
    __syncthreads();

    const float t00 = tm[0], t01 = tm[1], t02 = tm[2],  t03 = tm[3];
    const float t10 = tm[4], t11 = tm[5], t12 = tm[6],  t13 = tm[7];
    const float t20 = tm[8], t21 = tm[9], t22 = tm[10], t23 = tm[11];

    const int d0 = dblk << 3, h0 = hblk << 3, w0 = wblk << 5;
    const float inv = 2.0f / 127.0f;
    const float x0 = -1.f + d0 * inv, y0 = -1.f + h0 * inv, z0 = -1.f + w0 * inv;
    // pixel coords at tile origin; per-index pixel delta == t (inv*63.5 == 1)
    const float P0 = (t00 * x0 + t01 * y0 + t02 * z0 + t03 + 1.f) * 63.5f;
    const float P1 = (t10 * x0 + t11 * y0 + t12 * z0 + t13 + 1.f) * 63.5f;
    const float P2 = (t20 * x0 + t21 * y0 + t22 * z0 + t23 + 1.f) * 63.5f;

    // tile bounds via corner extremes (kd<=7, kh<=7, kw<=31)
    const float mn0 = P0 + fminf(0.f, 7.f*t00) + fminf(0.f, 7.f*t01) + fminf(0.f, 31.f*t02);
    const float mx0 = P0 + fmaxf(0.f, 7.f*t00) + fmaxf(0.f, 7.f*t01) + fmaxf(0.f, 31.f*t02);
    const float mn1 = P1 + fminf(0.f, 7.f*t10) + fminf(0.f, 7.f*t11) + fminf(0.f, 31.f*t12);
    const float mx1 = P1 + fmaxf(0.f, 7.f*t10) + fmaxf(0.f, 7.f*t11) + fmaxf(0.f, 31.f*t12);
    const float mn2 = P2 + fminf(0.f, 7.f*t20) + fminf(0.f, 7.f*t21) + fminf(0.f, 31.f*t22);
    const float mx2 = P2 + fmaxf(0.f, 7.f*t20) + fmaxf(0.f, 7.f*t21) + fmaxf(0.f, 31.f*t22);

    const int i0mn = (int)floorf(mn0), i0mx = (int)floorf(mx0);
    const int i1mn = (int)floorf(mn1), i1mx = (int)floorf(mx1);
    const int i2mn = (int)floorf(mn2), i2mx = (int)floorf(mx2);

    const int d_lo = min(max(i0mn - 1, 0), NS - SD);          // 0..114
    const int h_lo = min(max(i1mn - 1, 0), NS - SH);
    const int ws   = min(max(i2mn - 1, 0) & ~3, NS - ROW_W);  // 0..88, 16B aligned

    const int interior = __builtin_amdgcn_readfirstlane(
        (i0mn >= 0 && i0mx <= 126 && i1mn >= 0 && i1mx <= 126 &&
         i2mn >= 0 && i2mx <= 126) ? 1 : 0);
    // uniform offset folded into per-voxel address (scalarized)
    const int off = __builtin_amdgcn_readfirstlane(
        -(d_lo * RST + h_lo * ROW_W + ws));

    // ---- stage slab: SD*SH rows of ROW_W floats via global_load_lds x16 ----
    // lane-task: hi = tid/10, chunk = tid%10 (140 tasks); LDS float offset of
    // task = hi*40 + c*4 = 4*tid exactly, so wave LDS base = di*RST + 256*wave
    // (lane-contiguous, matches HW's base + lane*16B rule).
    {
        const float* gb = img + (size_t)b * VOX;
        const int hi = tid / 10;
        const int c  = tid - hi * 10;
        const int wvbase = (tid & ~63) << 2;                  // floats
        if (tid < SH * 10) {
#pragma unroll
            for (int di = 0; di < SD; ++di) {
                const float* g = gb + (((d_lo + di) * NS + (h_lo + hi)) * NS
                                       + ws + (c << 2));
                __builtin_amdgcn_global_load_lds(
                    (gconst_t*)g, (lds_t*)(slab + di * RST + wvbase), 16, 0, 0);
            }
        }
    }
    __syncthreads();

    // ---- compute: lanes dense along w (bank stride 1 -> <=2-way = free);
    //      8 voxels along d per thread ----
    const int wl = tid & 31, hh = tid >> 5;
    float q0 = P0 + hh * t01 + wl * t02;
    float q1 = P1 + hh * t11 + wl * t12;
    float q2 = P2 + hh * t21 + wl * t22;

    float res[8];

    if (interior) {
#pragma unroll
        for (int k = 0; k < 8; ++k) {
            float f0 = floorf(q0), f1 = floorf(q1), f2 = floorf(q2);
            int   i0 = (int)f0,    i1 = (int)f1,    i2 = (int)f2;
            float r0 = q0 - f0,    r1 = q1 - f1,    r2 = q2 - f2;

            int base = i0 * RST + i1 * ROW_W + i2 + off;      // RST/ROW_W const
            float a00 = slab[base],           b00 = slab[base + 1];
            float a01 = slab[base + ROW_W],   b01 = slab[base + ROW_W + 1];
            int base2 = base + RST;
            float a10 = slab[base2],          b10 = slab[base2 + 1];
            float a11 = slab[base2 + ROW_W],  b11 = slab[base2 + ROW_W + 1];

            float e0 = fmaf(r2, b00 - a00, a00);
            float e1 = fmaf(r2, b01 - a01, a01);
            float e2 = fmaf(r2, b10 - a10, a10);
            float e3 = fmaf(r2, b11 - a11, a11);
            float c0 = fmaf(r1, e1 - e0, e0);
            float c1 = fmaf(r1, e3 - e2, e2);
            res[k] = fmaf(r0, c1 - c0, c0);

            q0 += t00; q1 += t10; q2 += t20;
        }
    } else {
        // boundary: clip indices, zero weights (reference semantics); all
        // reads provably inside the staged window
#pragma unroll
        for (int k = 0; k < 8; ++k) {
            float f0 = floorf(q0), f1 = floorf(q1), f2 = floorf(q2);
            int   i0 = (int)f0,    i1 = (int)f1,    i2 = (int)f2;
            float r0 = q0 - f0,    r1 = q1 - f1,    r2 = q2 - f2;

            float wd0 = (i0 >= 0     && i0 < NS)     ? (1.0f - r0) : 0.0f;
            float wd1 = (i0 + 1 >= 0 && i0 + 1 < NS) ? r0          : 0.0f;
            float wh0 = (i1 >= 0     && i1 < NS)     ? (1.0f - r1) : 0.0f;
            float wh1 = (i1 + 1 >= 0 && i1 + 1 < NS) ? r1          : 0.0f;
            float ww0 = (i2 >= 0     && i2 < NS)     ? (1.0f - r2) : 0.0f;
            float ww1 = (i2 + 1 >= 0 && i2 + 1 < NS) ? r2          : 0.0f;

            int dI0 = min(max(min(max(i0,     0), NS - 1) - d_lo, 0), SD - 1);
            int dI1 = min(max(min(max(i0 + 1, 0), NS - 1) - d_lo, 0), SD - 1);
            int hI0 = min(max(min(max(i1,     0), NS - 1) - h_lo, 0), SH - 1);
            int hI1 = min(max(min(max(i1 + 1, 0), NS - 1) - h_lo, 0), SH - 1);
            int cw0 = min(max(i2,     0), NS - 1);
            int cw1 = min(max(i2 + 1, 0), NS - 1);
            int j0  = min(max(cw0 - ws, 0), ROW_W - 1);
            bool same = (cw1 == cw0);

            float acc = 0.f;
            {
                int bb = dI0 * RST + hI0 * ROW_W + j0;
                float a = slab[bb], bv = slab[bb + 1];
                float rt = same ? a : bv;
                acc = fmaf(fmaf(a, ww0, rt * ww1), wd0 * wh0, acc);
            }
            {
                int bb = dI0 * RST + hI1 * ROW_W + j0;
                float a = slab[bb], bv = slab[bb + 1];
                float rt = same ? a : bv;
                acc = fmaf(fmaf(a, ww0, rt * ww1), wd0 * wh1, acc);
            }
            {
                int bb = dI1 * RST + hI0 * ROW_W + j0;
                float a = slab[bb], bv = slab[bb + 1];
                float rt = same ? a : bv;
                acc = fmaf(fmaf(a, ww0, rt * ww1), wd1 * wh0, acc);
            }
            {
                int bb = dI1 * RST + hI1 * ROW_W + j0;
                float a = slab[bb], bv = slab[bb + 1];
                float rt = same ? a : bv;
                acc = fmaf(fmaf(a, ww0, rt * ww1), wd1 * wh1, acc);
            }
            res[k] = acc;

            q0 += t00; q1 += t10; q2 += t20;
        }
    }

    // stores: wave = 2 h-rows x 32 consecutive w -> coalesced segments
    size_t ob = (((size_t)(b * NS + d0) * NS + (h0 + hh)) * NS) + w0 + wl;
#pragma unroll
    for (int k = 0; k < 8; ++k)
        out[ob + (size_t)k * NS * NS] = res[k];
}

extern "C" void kernel_launch(void* const* d_in, const int* in_sizes, int n_in,
                              void* d_out, int out_size, void* d_ws, size_t ws_size,
                              hipStream_t stream) {
    const float* img = (const float*)d_in[0];   // [8,128,128,128,1] fp32
    const float* u   = (const float*)d_in[1];   // [8,8,3] fp32
    float* out = (float*)d_out;

    int blocks = NB * 16 * 16 * 4;              // 8,192 (4w x 16h x 16d tiles)
    warp_resample_kernel<<<blocks, 256, 0, stream>>>(img, u, out);
}

// Round 6
// 123.359 us; speedup vs baseline: 1.0909x; 1.0909x over previous
//
#include <hip/hip_runtime.h>

// input_tensor: [8,128,128,128,1] fp32 ; random_u: [8,8,3] fp32 ; SCALE=0.2
#define NB   8
#define NS   128
#define VOX  (NS*NS*NS)

// Tile 32w x 8h x 8d. Affine coeff bounds (A^T A = 8I closed form):
//   t_diag in [0.8,1.0], |t_offdiag| <= 0.1, |t_trans| <= 0.1.
// Pixel spans over tile offsets (kd<=7, kh<=7, kw<=31):
//   p0/p1 span <= 7*1 + 7*0.1 + 31*0.1 = 10.8 -> floor-index span <= 11
//     -> taps need rows [i0mn, i0mx+1] -> <= 13 rows
//   p2 span <= 32.4 -> floor span <= 33 -> cols [i2mn, i2mx+1] <= 35
//     -> +3 alignment loss -> 38 -> ROW_W=40 (16B-aligned staging chunks)
// Layout strides are compile-time (SD/SH fixed); only the STAGED row counts
// (Sd, Sh) are per-block variable -> minimal fetch + constant addressing.
#define SD    13
#define SH    13
#define ROW_W 40
#define RST   (SH*ROW_W)     // 520, compile-time constant

typedef __attribute__((address_space(1))) const void gconst_t;
typedef __attribute__((address_space(3))) void lds_t;

__global__ __launch_bounds__(256) void warp_resample_kernel(
        const float* __restrict__ img, const float* __restrict__ u,
        float* __restrict__ out) {
    __shared__ float tm[12];
    __shared__ __align__(16) float slab[SD * RST];   // 27,040 B -> 6 blocks/CU

    const int tid  = threadIdx.x;
    const int bi   = blockIdx.x;
    const int wblk =  bi       & 3;    // 4 w-tiles of 32
    const int hblk = (bi >> 2) & 15;   // 16 h-tiles of 8
    const int dblk = (bi >> 6) & 15;   // 16 d-tiles of 8
    const int b    =  bi >> 10;        // 8 batches

    // ---- affine transform from noise (A^T A = 8I -> closed form), 12 lanes ----
    if (tid < 12) {
        int i = tid >> 2, j = tid & 3;
        float acc = 0.f;
#pragma unroll
        for (int n = 0; n < 8; ++n) {
            float ci = (n & (4 >> i)) ? 1.f : -1.f;
            float cj = (j < 3) ? ((n & (4 >> j)) ? 1.f : -1.f) : 1.f;
            float s  = 0.8f + 0.2f * u[(b * 8 + n) * 3 + i];
            acc += cj * ci * s;
        }
        tm[tid] = acc * 0.125f;
    }
    __syncthreads();

    const float t00 = tm[0], t01 = tm[1], t02 = tm[2],  t03 = tm[3];
    const float t10 = tm[4], t11 = tm[5], t12 = tm[6],  t13 = tm[7];
    const float t20 = tm[8], t21 = tm[9], t22 = tm[10], t23 = tm[11];

    const int d0 = dblk << 3, h0 = hblk << 3, w0 = wblk << 5;
    const float inv = 2.0f / 127.0f;
    const float x0 = -1.f + d0 * inv, y0 = -1.f + h0 * inv, z0 = -1.f + w0 * inv;
    // pixel coords at tile origin; per-index pixel delta == t (inv*63.5 == 1)
    const float P0 = (t00 * x0 + t01 * y0 + t02 * z0 + t03 + 1.f) * 63.5f;
    const float P1 = (t10 * x0 + t11 * y0 + t12 * z0 + t13 + 1.f) * 63.5f;
    const float P2 = (t20 * x0 + t21 * y0 + t22 * z0 + t23 + 1.f) * 63.5f;

    // tile bounds via corner extremes (kd<=7, kh<=7, kw<=31)
    const float mn0 = P0 + fminf(0.f, 7.f*t00) + fminf(0.f, 7.f*t01) + fminf(0.f, 31.f*t02);
    const float mx0 = P0 + fmaxf(0.f, 7.f*t00) + fmaxf(0.f, 7.f*t01) + fmaxf(0.f, 31.f*t02);
    const float mn1 = P1 + fminf(0.f, 7.f*t10) + fminf(0.f, 7.f*t11) + fminf(0.f, 31.f*t12);
    const float mx1 = P1 + fmaxf(0.f, 7.f*t10) + fmaxf(0.f, 7.f*t11) + fmaxf(0.f, 31.f*t12);
    const float mn2 = P2 + fminf(0.f, 7.f*t20) + fminf(0.f, 7.f*t21) + fminf(0.f, 31.f*t22);
    const float mx2 = P2 + fmaxf(0.f, 7.f*t20) + fmaxf(0.f, 7.f*t21) + fmaxf(0.f, 31.f*t22);

    const int i0mn = (int)floorf(mn0), i0mx = (int)floorf(mx0);
    const int i1mn = (int)floorf(mn1), i1mx = (int)floorf(mx1);
    const int i2mn = (int)floorf(mn2), i2mx = (int)floorf(mx2);

    const int d_lo = min(max(i0mn, 0), NS - SD);              // 0..115
    const int h_lo = min(max(i1mn, 0), NS - SH);
    const int ws   = min(max(i2mn - 1, 0) & ~3, NS - ROW_W);  // 16B-aligned
    const int Sd   = min(i0mx + 2 - d_lo, SD);                // staged d-rows
    const int Sh   = min(i1mx + 2 - h_lo, SH);                // staged h-rows

    const int interior = __builtin_amdgcn_readfirstlane(
        (i0mn >= 0 && i0mx <= 126 && i1mn >= 0 && i1mx <= 126 &&
         i2mn >= 0 && i2mx <= 126) ? 1 : 0);
    const int off = __builtin_amdgcn_readfirstlane(
        -(d_lo * RST + h_lo * ROW_W + ws));

    // ---- stage slab: Sd*Sh rows of ROW_W floats via global_load_lds x16 ----
    // lane-task: hi = tid/10, chunk = tid%10; LDS float offset = 4*tid exactly,
    // so per-wave LDS base = di*RST + 256*wave (lane-contiguous base+lane*16B).
    {
        const float* gb = img + (size_t)b * VOX;
        const int hi = tid / 10;
        const int c  = tid - hi * 10;
        const int wvbase = (tid & ~63) << 2;                  // floats
        if (hi < Sh) {
            for (int di = 0; di < Sd; ++di) {
                const float* g = gb + (((d_lo + di) * NS + (h_lo + hi)) * NS
                                       + ws + (c << 2));
                __builtin_amdgcn_global_load_lds(
                    (gconst_t*)g, (lds_t*)(slab + di * RST + wvbase), 16, 0, 0);
            }
        }
    }
    __syncthreads();

    // ---- compute: lanes dense along w; 8 voxels along d per thread ----
    const int wl = tid & 31, hh = tid >> 5;
    float q0 = P0 + hh * t01 + wl * t02;
    float q1 = P1 + hh * t11 + wl * t12;
    float q2 = P2 + hh * t21 + wl * t22;

    float res[8];

    if (interior) {
        // all q >= 0 here -> (int)q == floor(q), fractf(q) == q - floor(q)
#pragma unroll
        for (int k = 0; k < 8; ++k) {
            int   i0 = (int)q0,  i1 = (int)q1,  i2 = (int)q2;
            float r0 = __builtin_amdgcn_fractf(q0);
            float r1 = __builtin_amdgcn_fractf(q1);
            float r2 = __builtin_amdgcn_fractf(q2);

            int base = i0 * RST + i1 * ROW_W + i2 + off;      // const strides
            float a00 = slab[base],           b00 = slab[base + 1];
            float a01 = slab[base + ROW_W],   b01 = slab[base + ROW_W + 1];
            int base2 = base + RST;
            float a10 = slab[base2],          b10 = slab[base2 + 1];
            float a11 = slab[base2 + ROW_W],  b11 = slab[base2 + ROW_W + 1];

            float e0 = fmaf(r2, b00 - a00, a00);
            float e1 = fmaf(r2, b01 - a01, a01);
            float e2 = fmaf(r2, b10 - a10, a10);
            float e3 = fmaf(r2, b11 - a11, a11);
            float c0 = fmaf(r1, e1 - e0, e0);
            float c1 = fmaf(r1, e3 - e2, e2);
            res[k] = fmaf(r0, c1 - c0, c0);

            q0 += t00; q1 += t10; q2 += t20;
        }
    } else {
        // boundary: clip indices, zero weights (reference semantics); every
        // nonzero-weight tap is provably inside the staged window
#pragma unroll
        for (int k = 0; k < 8; ++k) {
            float f0 = floorf(q0), f1 = floorf(q1), f2 = floorf(q2);
            int   i0 = (int)f0,    i1 = (int)f1,    i2 = (int)f2;
            float r0 = q0 - f0,    r1 = q1 - f1,    r2 = q2 - f2;

            float wd0 = (i0 >= 0     && i0 < NS)     ? (1.0f - r0) : 0.0f;
            float wd1 = (i0 + 1 >= 0 && i0 + 1 < NS) ? r0          : 0.0f;
            float wh0 = (i1 >= 0     && i1 < NS)     ? (1.0f - r1) : 0.0f;
            float wh1 = (i1 + 1 >= 0 && i1 + 1 < NS) ? r1          : 0.0f;
            float ww0 = (i2 >= 0     && i2 < NS)     ? (1.0f - r2) : 0.0f;
            float ww1 = (i2 + 1 >= 0 && i2 + 1 < NS) ? r2          : 0.0f;

            int dI0 = min(max(min(max(i0,     0), NS - 1) - d_lo, 0), Sd - 1);
            int dI1 = min(max(min(max(i0 + 1, 0), NS - 1) - d_lo, 0), Sd - 1);
            int hI0 = min(max(min(max(i1,     0), NS - 1) - h_lo, 0), Sh - 1);
            int hI1 = min(max(min(max(i1 + 1, 0), NS - 1) - h_lo, 0), Sh - 1);
            int cw0 = min(max(i2,     0), NS - 1);
            int cw1 = min(max(i2 + 1, 0), NS - 1);
            int j0  = min(max(cw0 - ws, 0), ROW_W - 1);
            bool same = (cw1 == cw0);

            float acc = 0.f;
            {
                int bb = dI0 * RST + hI0 * ROW_W + j0;
                float a = slab[bb], bv = slab[bb + 1];
                float rt = same ? a : bv;
                acc = fmaf(fmaf(a, ww0, rt * ww1), wd0 * wh0, acc);
            }
            {
                int bb = dI0 * RST + hI1 * ROW_W + j0;
                float a = slab[bb], bv = slab[bb + 1];
                float rt = same ? a : bv;
                acc = fmaf(fmaf(a, ww0, rt * ww1), wd0 * wh1, acc);
            }
            {
                int bb = dI1 * RST + hI0 * ROW_W + j0;
                float a = slab[bb], bv = slab[bb + 1];
                float rt = same ? a : bv;
                acc = fmaf(fmaf(a, ww0, rt * ww1), wd1 * wh0, acc);
            }
            {
                int bb = dI1 * RST + hI1 * ROW_W + j0;
                float a = slab[bb], bv = slab[bb + 1];
                float rt = same ? a : bv;
                acc = fmaf(fmaf(a, ww0, rt * ww1), wd1 * wh1, acc);
            }
            res[k] = acc;

            q0 += t00; q1 += t10; q2 += t20;
        }
    }

    // stores: wave = 2 h-rows x 32 consecutive w -> coalesced 128B segments
    size_t ob = (((size_t)(b * NS + d0) * NS + (h0 + hh)) * NS) + w0 + wl;
#pragma unroll
    for (int k = 0; k < 8; ++k)
        out[ob + (size_t)k * NS * NS] = res[k];
}

extern "C" void kernel_launch(void* const* d_in, const int* in_sizes, int n_in,
                              void* d_out, int out_size, void* d_ws, size_t ws_size,
                              hipStream_t stream) {
    const float* img = (const float*)d_in[0];   // [8,128,128,128,1] fp32
    const float* u   = (const float*)d_in[1];   // [8,8,3] fp32
    float* out = (float*)d_out;

    int blocks = NB * 16 * 16 * 4;              // 8,192 (4w x 16h x 16d tiles)
    warp_resample_kernel<<<blocks, 256, 0, stream>>>(img, u, out);
}